// Round 12
// baseline (1050.884 us; speedup 1.0000x reference)
//
#include <hip/hip_runtime.h>
#include <hip/hip_fp16.h>

typedef _Float16 half8 __attribute__((ext_vector_type(8)));
typedef float f32x4 __attribute__((ext_vector_type(4)));

// ---------------------------------------------------------------------------
// DistMultNN multi-kernel pipeline (MI355X) — ATTRIBUTION ROUND: GJ and cc
// split into separate dispatches (independent: GJ->VA, cc->XgA) so rocprof
// times each phase exactly. Internals byte-identical to round 11.
//   A1: gj_inv_kernel (1x1024)    blocked Gauss-Jordan inverse -> VA
//   A2: cc_kernel     (510x1024)  circcorr + x -> XgA (MFMA A-frag order)
//   B : ns_mt/ns_upd x2, compute_u, vhb_kernel
//   C : gemm_kernel   (2048x256)  MFMA Z=X*V + epilogue -> out
// ---------------------------------------------------------------------------

#define XSS 280      // xstage row stride (halfs) in gemm kernel

// ============ A1: blocked in-place Gauss-Jordan inverse (1 block) ===========
__global__ __launch_bounds__(1024, 4)
void gj_inv_kernel(const float* __restrict__ W, float* __restrict__ VA) {
  __shared__ float rowbuf[8][264];
  __shared__ float colbuf[256][8];
  const int tid = threadIdx.x;
  const int tx = tid & 31, ty = tid >> 5;
  const int r0 = ty << 3, gc0 = tx << 3;
  float gg[8][8];
#pragma unroll
  for (int i = 0; i < 8; ++i) {
    const float4 wa = *(const float4*)&W[(r0 + i) * 256 + gc0];
    const float4 wb = *(const float4*)&W[(r0 + i) * 256 + gc0 + 4];
    gg[i][0] = wa.x; gg[i][1] = wa.y; gg[i][2] = wa.z; gg[i][3] = wa.w;
    gg[i][4] = wb.x; gg[i][5] = wb.y; gg[i][6] = wb.z; gg[i][7] = wb.w;
#pragma unroll
    for (int j = 0; j < 8; ++j)
      if ((r0 + i) == (gc0 + j)) gg[i][j] -= 1.0f;
  }
  __syncthreads();
  for (int kg = 0; kg < 32; ++kg) {
    if (ty == kg) {
      const int L0 = (kg & 1) << 5;
#pragma unroll
      for (int kj = 0; kj < 8; ++kj) {
        float c[8];
#pragma unroll
        for (int i = 0; i < 8; ++i) c[i] = __shfl(gg[i][kj], L0 + kg, 64);
        const float pr = 1.0f / c[kj];
#pragma unroll
        for (int j = 0; j < 8; ++j) gg[kj][j] *= pr;
        if (tx == kg) gg[kj][kj] = pr;
#pragma unroll
        for (int i = 0; i < 8; ++i) {
          if (i == kj) continue;
#pragma unroll
          for (int j = 0; j < 8; ++j) gg[i][j] = fmaf(-c[i], gg[kj][j], gg[i][j]);
          if (tx == kg) gg[i][kj] = -c[i] * pr;
        }
      }
#pragma unroll
      for (int m = 0; m < 8; ++m) {
        float r4[8];
#pragma unroll
        for (int j = 0; j < 8; ++j)
          r4[j] = gg[m][j] + ((tx == kg && j == m) ? 1.0f : 0.0f);
        *(float4*)&rowbuf[m][gc0]     = make_float4(r4[0], r4[1], r4[2], r4[3]);
        *(float4*)&rowbuf[m][gc0 + 4] = make_float4(r4[4], r4[5], r4[6], r4[7]);
      }
    } else if (tx == kg) {
#pragma unroll
      for (int i = 0; i < 8; ++i) {
        *(float4*)&colbuf[r0 + i][0] = make_float4(gg[i][0], gg[i][1], gg[i][2], gg[i][3]);
        *(float4*)&colbuf[r0 + i][4] = make_float4(gg[i][4], gg[i][5], gg[i][6], gg[i][7]);
      }
    }
    __syncthreads();
    if (ty != kg) {
#pragma unroll
      for (int mp = 0; mp < 4; ++mp) {
        float ra[8], rb[8];
        {
          const float4 t0 = *(const float4*)&rowbuf[2 * mp][gc0];
          const float4 t1 = *(const float4*)&rowbuf[2 * mp][gc0 + 4];
          ra[0] = t0.x; ra[1] = t0.y; ra[2] = t0.z; ra[3] = t0.w;
          ra[4] = t1.x; ra[5] = t1.y; ra[6] = t1.z; ra[7] = t1.w;
          const float4 t2 = *(const float4*)&rowbuf[2 * mp + 1][gc0];
          const float4 t3 = *(const float4*)&rowbuf[2 * mp + 1][gc0 + 4];
          rb[0] = t2.x; rb[1] = t2.y; rb[2] = t2.z; rb[3] = t2.w;
          rb[4] = t3.x; rb[5] = t3.y; rb[6] = t3.z; rb[7] = t3.w;
        }
#pragma unroll
        for (int i = 0; i < 8; ++i) {
          const float2 fi = *(const float2*)&colbuf[r0 + i][2 * mp];
#pragma unroll
          for (int j = 0; j < 8; ++j) {
            gg[i][j] = fmaf(-fi.x, ra[j], gg[i][j]);
            gg[i][j] = fmaf(-fi.y, rb[j], gg[i][j]);
          }
        }
      }
    }
    __syncthreads();
  }
#pragma unroll
  for (int i = 0; i < 8; ++i) {
    *(float4*)&VA[(r0 + i) * 256 + gc0]     = make_float4(gg[i][0], gg[i][1], gg[i][2], gg[i][3]);
    *(float4*)&VA[(r0 + i) * 256 + gc0 + 4] = make_float4(gg[i][4], gg[i][5], gg[i][6], gg[i][7]);
  }
}

// ============ A2: cc + x -> XgA (round-11 internals, 510 blocks) ============
__global__ __launch_bounds__(1024, 8)
void cc_kernel(const float* __restrict__ E_ent, const float* __restrict__ E_rel,
               const int* __restrict__ samples, __half* __restrict__ XgA) {
  __shared__ float regionY[16384];   // e1buf 32x256 swz | e2buf 32x256 swz
  const int tid = threadIdx.x;
  const int bid = blockIdx.x;        // 0..509  (== round-11 blk-1)

  const int g = tid & 31, l5 = tid >> 5, k0 = l5 << 3;
  const int sw = g & 7;
  const int ss = tid >> 5;
  const int sws = ss & 7;
  const int uw0 = (tid & 31) << 1;
  const int kkf = l5 >> 2, lhf = l5 & 3;
  const int rtf = g >> 4, lanef = (lhf << 4) | (g & 15);
  float* const e1w = &regionY[ss * 256];
  float* const e2w = &regionY[8192 + ss * 256];
  const float* const e1r = &regionY[g * 256];
  const float* const e2r = &regionY[8192 + g * 256];
  const int nb = (bid < 8) ? 5 : 4;

  for (int t = 0; t < nb; ++t) {
    const int gb = (t < 4) ? (bid * 4 + t) : (2040 + bid);
    const int sb = gb << 5;
    __syncthreads();
    {
      const int ie1 = samples[(sb + ss) * 3 + 0];
      const int ie2 = samples[(sb + ss) * 3 + 2];
      const float* p1 = E_ent + (size_t)ie1 * 256 + (uw0 << 2);
      const float* p2 = E_ent + (size_t)ie2 * 256 + (uw0 << 2);
      *(float4*)&e1w[((uw0 ^ sws) << 2)]       = *(const float4*)&p1[0];
      *(float4*)&e1w[(((uw0 + 1) ^ sws) << 2)] = *(const float4*)&p1[4];
      *(float4*)&e2w[((uw0 ^ sws) << 2)]       = *(const float4*)&p2[0];
      *(float4*)&e2w[(((uw0 + 1) ^ sws) << 2)] = *(const float4*)&p2[4];
    }
    __syncthreads();
    float acc[8] = {};
    float wlo[8], whi[8];
    {
      const int ul = k0 >> 2;
      const int uh = ((k0 + 8) & 255) >> 2;
      const float4 a = *(const float4*)&e2r[((ul ^ sw) << 2)];
      const float4 b = *(const float4*)&e2r[(((ul + 1) ^ sw) << 2)];
      const float4 c = *(const float4*)&e2r[((uh ^ sw) << 2)];
      const float4 d = *(const float4*)&e2r[(((uh + 1) ^ sw) << 2)];
      wlo[0] = a.x; wlo[1] = a.y; wlo[2] = a.z; wlo[3] = a.w;
      wlo[4] = b.x; wlo[5] = b.y; wlo[6] = b.z; wlo[7] = b.w;
      whi[0] = c.x; whi[1] = c.y; whi[2] = c.z; whi[3] = c.w;
      whi[4] = d.x; whi[5] = d.y; whi[6] = d.z; whi[7] = d.w;
    }
#pragma unroll 4
    for (int i = 0; i < 32; ++i) {
      float e1v[8];
      {
        const int u = i << 1;
        const float4 a = *(const float4*)&e1r[((u ^ sw) << 2)];
        const float4 b = *(const float4*)&e1r[(((u + 1) ^ sw) << 2)];
        e1v[0] = a.x; e1v[1] = a.y; e1v[2] = a.z; e1v[3] = a.w;
        e1v[4] = b.x; e1v[5] = b.y; e1v[6] = b.z; e1v[7] = b.w;
      }
      float wnx[8];
      {
        const int hn = ((i << 3) + k0 + 16) & 255;
        const int u = hn >> 2;
        const float4 a = *(const float4*)&e2r[((u ^ sw) << 2)];
        const float4 b = *(const float4*)&e2r[(((u + 1) ^ sw) << 2)];
        wnx[0] = a.x; wnx[1] = a.y; wnx[2] = a.z; wnx[3] = a.w;
        wnx[4] = b.x; wnx[5] = b.y; wnx[6] = b.z; wnx[7] = b.w;
      }
#pragma unroll
      for (int m = 0; m < 8; ++m) {
#pragma unroll
        for (int jj = 0; jj < 8; ++jj) {
          const int idx = jj + m;
          const float wv = (idx < 8) ? wlo[idx] : whi[idx - 8];
          acc[m] = fmaf(e1v[jj], wv, acc[m]);
        }
      }
#pragma unroll
      for (int q = 0; q < 8; ++q) { wlo[q] = whi[q]; whi[q] = wnx[q]; }
    }
    const int ir = samples[(sb + g) * 3 + 1];
    const float* rp = E_rel + (size_t)ir * 256 + k0;
    const float4 r0v = *(const float4*)&rp[0];
    const float4 r1v = *(const float4*)&rp[4];
    union { __half2 h2[4]; uint4 u4; } cv;
    cv.h2[0] = __floats2half2_rn(r0v.x * acc[0], r0v.y * acc[1]);
    cv.h2[1] = __floats2half2_rn(r0v.z * acc[2], r0v.w * acc[3]);
    cv.h2[2] = __floats2half2_rn(r1v.x * acc[4], r1v.y * acc[5]);
    cv.h2[3] = __floats2half2_rn(r1v.z * acc[6], r1v.w * acc[7]);
    *(uint4*)&XgA[((size_t)((gb * 2 + rtf) * 8 + kkf) * 64 + lanef) * 8] = cv.u4;
  }
}

// ============ B: Newton-Schulz polish + u + VhB (unchanged) =================
__global__ __launch_bounds__(64) void ns_mt_kernel(const float* __restrict__ W,
                                                   const float* __restrict__ Vin,
                                                   float* __restrict__ T) {
  const int bi = blockIdx.x >> 3, bj = blockIdx.x & 7;
  const int ti = threadIdx.x >> 3, tj = threadIdx.x & 7;
  const int i0 = bi * 32 + ti * 4, j0 = bj * 32 + tj * 4;
  float acc[4][4] = {};
  for (int k = 0; k < 256; ++k) {
    float4 a4 = *(const float4*)&W[k * 256 + i0];
    float a[4] = {a4.x, a4.y, a4.z, a4.w};
#pragma unroll
    for (int i = 0; i < 4; ++i) a[i] -= ((i0 + i) == k) ? 1.0f : 0.0f;
    float4 b4 = *(const float4*)&Vin[k * 256 + j0];
    const float b[4] = {b4.x, b4.y, b4.z, b4.w};
#pragma unroll
    for (int i = 0; i < 4; ++i)
#pragma unroll
      for (int j = 0; j < 4; ++j) acc[i][j] += a[i] * b[j];
  }
#pragma unroll
  for (int i = 0; i < 4; ++i)
    *(float4*)&T[(i0 + i) * 256 + j0] =
        make_float4(acc[i][0], acc[i][1], acc[i][2], acc[i][3]);
}

__global__ __launch_bounds__(64) void ns_upd_kernel(const float* __restrict__ Vin,
                                                    const float* __restrict__ T,
                                                    float* __restrict__ Vout) {
  const int bi = blockIdx.x >> 3, bj = blockIdx.x & 7;
  const int ti = threadIdx.x >> 3, tj = threadIdx.x & 7;
  const int i0 = bi * 32 + ti * 4, j0 = bj * 32 + tj * 4;
  float acc[4][4] = {};
  for (int k = 0; k < 256; ++k) {
    float a[4];
#pragma unroll
    for (int i = 0; i < 4; ++i) a[i] = Vin[(i0 + i) * 256 + k];
    float4 b4 = *(const float4*)&T[k * 256 + j0];
    const float b[4] = {b4.x, b4.y, b4.z, b4.w};
#pragma unroll
    for (int i = 0; i < 4; ++i)
#pragma unroll
      for (int j = 0; j < 4; ++j) acc[i][j] += a[i] * b[j];
  }
#pragma unroll
  for (int i = 0; i < 4; ++i) {
    float4 v = *(const float4*)&Vin[(i0 + i) * 256 + j0];
    *(float4*)&Vout[(i0 + i) * 256 + j0] =
        make_float4(2.0f * v.x - acc[i][0], 2.0f * v.y - acc[i][1],
                    2.0f * v.z - acc[i][2], 2.0f * v.w - acc[i][3]);
  }
}

__global__ __launch_bounds__(256) void compute_u_kernel(const float* __restrict__ V,
                                                        const float* __restrict__ b,
                                                        float* __restrict__ u,
                                                        float* __restrict__ c0) {
  const int tid = threadIdx.x;
  __shared__ float bs[256];
  __shared__ float us[256];
  bs[tid] = b[tid];
  __syncthreads();
  float acc = 0.0f;
  for (int j = 0; j < 256; j += 4) {
    float4 v4 = *(const float4*)&V[tid * 256 + j];
    acc += v4.x * bs[j] + v4.y * bs[j + 1] + v4.z * bs[j + 2] + v4.w * bs[j + 3];
  }
  u[tid] = acc;
  us[tid] = acc * bs[tid];
  __syncthreads();
  if (tid < 64) {
    float s = us[tid] + us[tid + 64] + us[tid + 128] + us[tid + 192];
#pragma unroll
    for (int off = 32; off > 0; off >>= 1) s += __shfl_down(s, off);
    if (tid == 0) c0[0] = s;
  }
}

__global__ __launch_bounds__(1024) void vhb_kernel(const float* __restrict__ VA,
                                                   __half* __restrict__ VhB) {
  const int ct = blockIdx.x;
  const int tid = threadIdx.x;
  const int kk = tid >> 7, rem = tid & 127;
  const int l = rem >> 1, e0 = (tid & 1) * 4;
  const float4 v4 = *(const float4*)&VA[(ct * 16 + (l & 15)) * 256 + kk * 32 + (l >> 4) * 8 + e0];
  __half* dst = VhB + ((size_t)(ct * 8 + kk) * 64 + l) * 8 + e0;
  *(__half2*)&dst[0] = __floats2half2_rn(v4.x, v4.y);
  *(__half2*)&dst[2] = __floats2half2_rn(v4.z, v4.w);
}

// ============ C: MFMA GEMM + epilogue, one batch per block (unchanged) ======
__global__ __launch_bounds__(256, 4)
void gemm_kernel(const __half* __restrict__ XgA, const __half* __restrict__ VhB,
                 const float* __restrict__ ub, const float* __restrict__ c0g,
                 float* __restrict__ out) {
  __shared__ __half xstage[32][XSS];
  __shared__ float ubuf[256];
  __shared__ float redbuf[2][16][4];

  const int tid = threadIdx.x;
  const int gb = blockIdx.x;
  const int w = tid >> 6, l = tid & 63;
  const int rt = w >> 1, ch = w & 1;
  const int lm = l & 15, lh = l >> 4;

  if (tid < 256) ubuf[tid] = ub[tid];
  if (tid < 128) ((float*)redbuf)[tid] = 0.f;

  const __half* ap = XgA + (size_t)(gb * 2 + rt) * 4096 + l * 8;
  half8 afr[8];
#pragma unroll
  for (int kk = 0; kk < 8; ++kk) afr[kk] = *(const half8*)&ap[kk * 512];
  if (ch == 0) {
#pragma unroll
    for (int kk = 0; kk < 8; ++kk)
      *(half8*)&xstage[rt * 16 + lm][kk * 32 + lh * 8] = afr[kk];
  }
  __syncthreads();

  f32x4 z[8];
#pragma unroll
  for (int j = 0; j < 8; ++j) z[j] = (f32x4){0.f, 0.f, 0.f, 0.f};
#pragma unroll
  for (int kk = 0; kk < 8; ++kk) {
    half8 bfr[8];
#pragma unroll
    for (int j = 0; j < 8; ++j) {
      const int ct = ch * 8 + j;
      bfr[j] = *(const half8*)&VhB[((size_t)(ct * 8 + kk) * 64 + l) * 8];
    }
#pragma unroll
    for (int j = 0; j < 8; ++j)
      z[j] = __builtin_amdgcn_mfma_f32_16x16x32_f16(afr[kk], bfr[j], z[j], 0, 0, 0);
  }

  float dp[4] = {}, dxx[4] = {}, dux[4] = {};
#pragma unroll
  for (int j = 0; j < 8; ++j) {
    const int col = (ch * 8 + j) * 16 + lm;
    const float uu = ubuf[col];
#pragma unroll
    for (int r = 0; r < 4; ++r) {
      const int s = rt * 16 + lh * 4 + r;
      const float xv = __half2float(xstage[s][col]);
      dp[r]  = fmaf(z[j][r], xv, dp[r]);
      dxx[r] = fmaf(xv, xv, dxx[r]);
      dux[r] = fmaf(uu, xv, dux[r]);
    }
  }
#pragma unroll
  for (int off = 1; off < 16; off <<= 1)
#pragma unroll
    for (int r = 0; r < 4; ++r) {
      dp[r]  += __shfl_xor(dp[r], off);
      dxx[r] += __shfl_xor(dxx[r], off);
      dux[r] += __shfl_xor(dux[r], off);
    }
  if (lm == 0) {
#pragma unroll
    for (int r = 0; r < 4; ++r) {
      atomicAdd(&redbuf[rt][lh * 4 + r][0], dp[r]);
      atomicAdd(&redbuf[rt][lh * 4 + r][1], dxx[r]);
      atomicAdd(&redbuf[rt][lh * 4 + r][2], dux[r]);
    }
  }
  __syncthreads();
  if (tid < 32) {
    const float c0v = c0g[0];
    const int rr = tid >> 4, si = tid & 15;
    const float* rv = redbuf[rr][si];
    out[gb * 32 + rr * 16 + si] = 3.0f * rv[0] - rv[2] - 0.25f * c0v - rv[1];
  }
}

// ============================ launcher ======================================
extern "C" void kernel_launch(void* const* d_in, const int* in_sizes, int n_in,
                              void* d_out, int out_size, void* d_ws, size_t ws_size,
                              hipStream_t stream) {
  const float* E_ent   = (const float*)d_in[0];
  const float* E_rel   = (const float*)d_in[1];
  const float* W       = (const float*)d_in[2];
  const float* bvec    = (const float*)d_in[3];
  const int*   samples = (const int*)d_in[4];
  float* out = (float*)d_out;
  float* ws  = (float*)d_ws;

  float* VA = ws;                      // 65536 f32 (final V)
  float* VB = ws + 65536;              // NS scratch T
  float* VC = ws + 131072;             // NS intermediate
  float* ub = ws + 196608;             // 256
  float* c0 = ws + 196864;             // 1 (+pad)
  __half* VhB = (__half*)(ws + 197120);// 131072 f16 = 256 KB (fragment order)
  __half* XgA = (__half*)(ws + 262656);// 16.78M f16 = 33.5 MB (A fragments)

  cc_kernel<<<510, 1024, 0, stream>>>(E_ent, E_rel, samples, XgA);
  gj_inv_kernel<<<1, 1024, 0, stream>>>(W, VA);
  ns_mt_kernel<<<64, 64, 0, stream>>>(W, VA, VB);
  ns_upd_kernel<<<64, 64, 0, stream>>>(VA, VB, VC);
  ns_mt_kernel<<<64, 64, 0, stream>>>(W, VC, VB);
  ns_upd_kernel<<<64, 64, 0, stream>>>(VC, VB, VA);
  compute_u_kernel<<<1, 256, 0, stream>>>(VA, bvec, ub, c0);
  vhb_kernel<<<16, 1024, 0, stream>>>(VA, VhB);
  gemm_kernel<<<2048, 256, 0, stream>>>(XgA, VhB, ub, c0, out);
}

// Round 13
// 402.665 us; speedup vs baseline: 2.6098x; 2.6098x over previous
//
#include <hip/hip_runtime.h>
#include <hip/hip_fp16.h>

typedef _Float16 half8 __attribute__((ext_vector_type(8)));
typedef float f32x4 __attribute__((ext_vector_type(4)));

// ---------------------------------------------------------------------------
// DistMultNN multi-kernel pipeline (MI355X).
// out[s] = 3*x^T V x - (Vb).x - 0.25*(b^T V b) - x.x, x = r*circcorr(e1,e2)
//   A: phase1_kernel (511x1024): GJ inverse on block 0 (ROUND-3-EXACT phase-B:
//      b32 colbuf broadcasts, measured 355us standalone; the round-5 float2
//      variant measured 750us in r12) || cc->XgA on blocks 1..510 (hidden).
//   B: ns_mt/ns_upd x2, compute_u, vhb_kernel (small)
//   C: gemm_kernel (2048x256) MFMA Z=X*V + epilogue -> out
// ---------------------------------------------------------------------------

#define XSS 280      // xstage row stride (halfs) in gemm kernel

// ============ A: GJ (block 0) || cc+x -> XgA (blocks 1..510) ================
__global__ __launch_bounds__(1024, 4)
void phase1_kernel(const float* __restrict__ E_ent, const float* __restrict__ E_rel,
                   const float* __restrict__ W, const int* __restrict__ samples,
                   float* __restrict__ VA, __half* __restrict__ XgA) {
  // union: GJ rowbuf(8x264)+colbuf(256x8) | cc e1buf+e2buf (2x 32x256 swz)
  __shared__ float regionY[16384];
  const int tid = threadIdx.x;
  const int blk = blockIdx.x;

  if (blk == 0) {
    // ---- blocked in-place Gauss-Jordan: ROUND-3-EXACT code (355us) ----
    const int tx = tid & 31, ty = tid >> 5;
    const int r0 = ty << 3, gc0 = tx << 3;
    float (*rowbuf)[264] = (float(*)[264])&regionY[0];        // 8 x 264
    float (*colbuf)[8]   = (float(*)[8])&regionY[8 * 264];    // 256 x 8
    float gg[8][8];
#pragma unroll
    for (int i = 0; i < 8; ++i) {
      const float4 wa = *(const float4*)&W[(r0 + i) * 256 + gc0];
      const float4 wb = *(const float4*)&W[(r0 + i) * 256 + gc0 + 4];
      gg[i][0] = wa.x; gg[i][1] = wa.y; gg[i][2] = wa.z; gg[i][3] = wa.w;
      gg[i][4] = wb.x; gg[i][5] = wb.y; gg[i][6] = wb.z; gg[i][7] = wb.w;
#pragma unroll
      for (int j = 0; j < 8; ++j)
        if ((r0 + i) == (gc0 + j)) gg[i][j] -= 1.0f;
    }
    __syncthreads();
    for (int kg = 0; kg < 32; ++kg) {
      if (ty == kg) {
        const int L0 = (kg & 1) << 5;
#pragma unroll
        for (int kj = 0; kj < 8; ++kj) {
          float c[8];
#pragma unroll
          for (int i = 0; i < 8; ++i) c[i] = __shfl(gg[i][kj], L0 + kg, 64);
          const float pr = 1.0f / c[kj];
#pragma unroll
          for (int j = 0; j < 8; ++j) gg[kj][j] *= pr;
          if (tx == kg) gg[kj][kj] = pr;
#pragma unroll
          for (int i = 0; i < 8; ++i) {
            if (i == kj) continue;
#pragma unroll
            for (int j = 0; j < 8; ++j) gg[i][j] = fmaf(-c[i], gg[kj][j], gg[i][j]);
            if (tx == kg) gg[i][kj] = -c[i] * pr;
          }
        }
#pragma unroll
        for (int m = 0; m < 8; ++m) {
          float r4[8];
#pragma unroll
          for (int j = 0; j < 8; ++j)
            r4[j] = gg[m][j] + ((tx == kg && j == m) ? 1.0f : 0.0f);
          *(float4*)&rowbuf[m][gc0]     = make_float4(r4[0], r4[1], r4[2], r4[3]);
          *(float4*)&rowbuf[m][gc0 + 4] = make_float4(r4[4], r4[5], r4[6], r4[7]);
        }
      } else if (tx == kg) {
#pragma unroll
        for (int i = 0; i < 8; ++i) {
          *(float4*)&colbuf[r0 + i][0] = make_float4(gg[i][0], gg[i][1], gg[i][2], gg[i][3]);
          *(float4*)&colbuf[r0 + i][4] = make_float4(gg[i][4], gg[i][5], gg[i][6], gg[i][7]);
        }
      }
      __syncthreads();
      if (ty != kg) {
        // ROUND-3-EXACT phase B: m-loop of 8, b32 colbuf broadcast reads.
#pragma unroll
        for (int m = 0; m < 8; ++m) {
          float rm[8];
          {
            const float4 t0 = *(const float4*)&rowbuf[m][gc0];
            const float4 t1 = *(const float4*)&rowbuf[m][gc0 + 4];
            rm[0] = t0.x; rm[1] = t0.y; rm[2] = t0.z; rm[3] = t0.w;
            rm[4] = t1.x; rm[5] = t1.y; rm[6] = t1.z; rm[7] = t1.w;
          }
#pragma unroll
          for (int i = 0; i < 8; ++i) {
            const float f = colbuf[r0 + i][m];   // 32-lane broadcast b32
#pragma unroll
            for (int j = 0; j < 8; ++j) gg[i][j] = fmaf(-f, rm[j], gg[i][j]);
          }
        }
      }
      __syncthreads();
    }
#pragma unroll
    for (int i = 0; i < 8; ++i) {
      *(float4*)&VA[(r0 + i) * 256 + gc0]     = make_float4(gg[i][0], gg[i][1], gg[i][2], gg[i][3]);
      *(float4*)&VA[(r0 + i) * 256 + gc0 + 4] = make_float4(gg[i][4], gg[i][5], gg[i][6], gg[i][7]);
    }
  } else {
    // ---- cc + x -> XgA (round-11 internals; measured ~230-250us r12) ----
    const int g = tid & 31, l5 = tid >> 5, k0 = l5 << 3;
    const int sw = g & 7;
    const int ss = tid >> 5;
    const int sws = ss & 7;
    const int uw0 = (tid & 31) << 1;
    const int kkf = l5 >> 2, lhf = l5 & 3;
    const int rtf = g >> 4, lanef = (lhf << 4) | (g & 15);
    float* const e1w = &regionY[ss * 256];
    float* const e2w = &regionY[8192 + ss * 256];
    const float* const e1r = &regionY[g * 256];
    const float* const e2r = &regionY[8192 + g * 256];
    const int bid = blk - 1;           // 0..509
    const int nb = (bid < 8) ? 5 : 4;

    for (int t = 0; t < nb; ++t) {
      const int gb = (t < 4) ? (bid * 4 + t) : (2040 + bid);
      const int sb = gb << 5;
      __syncthreads();
      {
        const int ie1 = samples[(sb + ss) * 3 + 0];
        const int ie2 = samples[(sb + ss) * 3 + 2];
        const float* p1 = E_ent + (size_t)ie1 * 256 + (uw0 << 2);
        const float* p2 = E_ent + (size_t)ie2 * 256 + (uw0 << 2);
        *(float4*)&e1w[((uw0 ^ sws) << 2)]       = *(const float4*)&p1[0];
        *(float4*)&e1w[(((uw0 + 1) ^ sws) << 2)] = *(const float4*)&p1[4];
        *(float4*)&e2w[((uw0 ^ sws) << 2)]       = *(const float4*)&p2[0];
        *(float4*)&e2w[(((uw0 + 1) ^ sws) << 2)] = *(const float4*)&p2[4];
      }
      __syncthreads();
      float acc[8] = {};
      float wlo[8], whi[8];
      {
        const int ul = k0 >> 2;
        const int uh = ((k0 + 8) & 255) >> 2;
        const float4 a = *(const float4*)&e2r[((ul ^ sw) << 2)];
        const float4 b = *(const float4*)&e2r[(((ul + 1) ^ sw) << 2)];
        const float4 c = *(const float4*)&e2r[((uh ^ sw) << 2)];
        const float4 d = *(const float4*)&e2r[(((uh + 1) ^ sw) << 2)];
        wlo[0] = a.x; wlo[1] = a.y; wlo[2] = a.z; wlo[3] = a.w;
        wlo[4] = b.x; wlo[5] = b.y; wlo[6] = b.z; wlo[7] = b.w;
        whi[0] = c.x; whi[1] = c.y; whi[2] = c.z; whi[3] = c.w;
        whi[4] = d.x; whi[5] = d.y; whi[6] = d.z; whi[7] = d.w;
      }
#pragma unroll 4
      for (int i = 0; i < 32; ++i) {
        float e1v[8];
        {
          const int u = i << 1;
          const float4 a = *(const float4*)&e1r[((u ^ sw) << 2)];
          const float4 b = *(const float4*)&e1r[(((u + 1) ^ sw) << 2)];
          e1v[0] = a.x; e1v[1] = a.y; e1v[2] = a.z; e1v[3] = a.w;
          e1v[4] = b.x; e1v[5] = b.y; e1v[6] = b.z; e1v[7] = b.w;
        }
        float wnx[8];
        {
          const int hn = ((i << 3) + k0 + 16) & 255;
          const int u = hn >> 2;
          const float4 a = *(const float4*)&e2r[((u ^ sw) << 2)];
          const float4 b = *(const float4*)&e2r[(((u + 1) ^ sw) << 2)];
          wnx[0] = a.x; wnx[1] = a.y; wnx[2] = a.z; wnx[3] = a.w;
          wnx[4] = b.x; wnx[5] = b.y; wnx[6] = b.z; wnx[7] = b.w;
        }
#pragma unroll
        for (int m = 0; m < 8; ++m) {
#pragma unroll
          for (int jj = 0; jj < 8; ++jj) {
            const int idx = jj + m;
            const float wv = (idx < 8) ? wlo[idx] : whi[idx - 8];
            acc[m] = fmaf(e1v[jj], wv, acc[m]);
          }
        }
#pragma unroll
        for (int q = 0; q < 8; ++q) { wlo[q] = whi[q]; whi[q] = wnx[q]; }
      }
      const int ir = samples[(sb + g) * 3 + 1];
      const float* rp = E_rel + (size_t)ir * 256 + k0;
      const float4 r0v = *(const float4*)&rp[0];
      const float4 r1v = *(const float4*)&rp[4];
      union { __half2 h2[4]; uint4 u4; } cv;
      cv.h2[0] = __floats2half2_rn(r0v.x * acc[0], r0v.y * acc[1]);
      cv.h2[1] = __floats2half2_rn(r0v.z * acc[2], r0v.w * acc[3]);
      cv.h2[2] = __floats2half2_rn(r1v.x * acc[4], r1v.y * acc[5]);
      cv.h2[3] = __floats2half2_rn(r1v.z * acc[6], r1v.w * acc[7]);
      *(uint4*)&XgA[((size_t)((gb * 2 + rtf) * 8 + kkf) * 64 + lanef) * 8] = cv.u4;
    }
  }
}

// ============ B: Newton-Schulz polish + u + VhB (unchanged) =================
__global__ __launch_bounds__(64) void ns_mt_kernel(const float* __restrict__ W,
                                                   const float* __restrict__ Vin,
                                                   float* __restrict__ T) {
  const int bi = blockIdx.x >> 3, bj = blockIdx.x & 7;
  const int ti = threadIdx.x >> 3, tj = threadIdx.x & 7;
  const int i0 = bi * 32 + ti * 4, j0 = bj * 32 + tj * 4;
  float acc[4][4] = {};
  for (int k = 0; k < 256; ++k) {
    float4 a4 = *(const float4*)&W[k * 256 + i0];
    float a[4] = {a4.x, a4.y, a4.z, a4.w};
#pragma unroll
    for (int i = 0; i < 4; ++i) a[i] -= ((i0 + i) == k) ? 1.0f : 0.0f;
    float4 b4 = *(const float4*)&Vin[k * 256 + j0];
    const float b[4] = {b4.x, b4.y, b4.z, b4.w};
#pragma unroll
    for (int i = 0; i < 4; ++i)
#pragma unroll
      for (int j = 0; j < 4; ++j) acc[i][j] += a[i] * b[j];
  }
#pragma unroll
  for (int i = 0; i < 4; ++i)
    *(float4*)&T[(i0 + i) * 256 + j0] =
        make_float4(acc[i][0], acc[i][1], acc[i][2], acc[i][3]);
}

__global__ __launch_bounds__(64) void ns_upd_kernel(const float* __restrict__ Vin,
                                                    const float* __restrict__ T,
                                                    float* __restrict__ Vout) {
  const int bi = blockIdx.x >> 3, bj = blockIdx.x & 7;
  const int ti = threadIdx.x >> 3, tj = threadIdx.x & 7;
  const int i0 = bi * 32 + ti * 4, j0 = bj * 32 + tj * 4;
  float acc[4][4] = {};
  for (int k = 0; k < 256; ++k) {
    float a[4];
#pragma unroll
    for (int i = 0; i < 4; ++i) a[i] = Vin[(i0 + i) * 256 + k];
    float4 b4 = *(const float4*)&T[k * 256 + j0];
    const float b[4] = {b4.x, b4.y, b4.z, b4.w};
#pragma unroll
    for (int i = 0; i < 4; ++i)
#pragma unroll
      for (int j = 0; j < 4; ++j) acc[i][j] += a[i] * b[j];
  }
#pragma unroll
  for (int i = 0; i < 4; ++i) {
    float4 v = *(const float4*)&Vin[(i0 + i) * 256 + j0];
    *(float4*)&Vout[(i0 + i) * 256 + j0] =
        make_float4(2.0f * v.x - acc[i][0], 2.0f * v.y - acc[i][1],
                    2.0f * v.z - acc[i][2], 2.0f * v.w - acc[i][3]);
  }
}

__global__ __launch_bounds__(256) void compute_u_kernel(const float* __restrict__ V,
                                                        const float* __restrict__ b,
                                                        float* __restrict__ u,
                                                        float* __restrict__ c0) {
  const int tid = threadIdx.x;
  __shared__ float bs[256];
  __shared__ float us[256];
  bs[tid] = b[tid];
  __syncthreads();
  float acc = 0.0f;
  for (int j = 0; j < 256; j += 4) {
    float4 v4 = *(const float4*)&V[tid * 256 + j];
    acc += v4.x * bs[j] + v4.y * bs[j + 1] + v4.z * bs[j + 2] + v4.w * bs[j + 3];
  }
  u[tid] = acc;
  us[tid] = acc * bs[tid];
  __syncthreads();
  if (tid < 64) {
    float s = us[tid] + us[tid + 64] + us[tid + 128] + us[tid + 192];
#pragma unroll
    for (int off = 32; off > 0; off >>= 1) s += __shfl_down(s, off);
    if (tid == 0) c0[0] = s;
  }
}

__global__ __launch_bounds__(1024) void vhb_kernel(const float* __restrict__ VA,
                                                   __half* __restrict__ VhB) {
  const int ct = blockIdx.x;
  const int tid = threadIdx.x;
  const int kk = tid >> 7, rem = tid & 127;
  const int l = rem >> 1, e0 = (tid & 1) * 4;
  const float4 v4 = *(const float4*)&VA[(ct * 16 + (l & 15)) * 256 + kk * 32 + (l >> 4) * 8 + e0];
  __half* dst = VhB + ((size_t)(ct * 8 + kk) * 64 + l) * 8 + e0;
  *(__half2*)&dst[0] = __floats2half2_rn(v4.x, v4.y);
  *(__half2*)&dst[2] = __floats2half2_rn(v4.z, v4.w);
}

// ============ C: MFMA GEMM + epilogue, one batch per block (unchanged) ======
__global__ __launch_bounds__(256, 4)
void gemm_kernel(const __half* __restrict__ XgA, const __half* __restrict__ VhB,
                 const float* __restrict__ ub, const float* __restrict__ c0g,
                 float* __restrict__ out) {
  __shared__ __half xstage[32][XSS];
  __shared__ float ubuf[256];
  __shared__ float redbuf[2][16][4];

  const int tid = threadIdx.x;
  const int gb = blockIdx.x;
  const int w = tid >> 6, l = tid & 63;
  const int rt = w >> 1, ch = w & 1;
  const int lm = l & 15, lh = l >> 4;

  if (tid < 256) ubuf[tid] = ub[tid];
  if (tid < 128) ((float*)redbuf)[tid] = 0.f;

  const __half* ap = XgA + (size_t)(gb * 2 + rt) * 4096 + l * 8;
  half8 afr[8];
#pragma unroll
  for (int kk = 0; kk < 8; ++kk) afr[kk] = *(const half8*)&ap[kk * 512];
  if (ch == 0) {
#pragma unroll
    for (int kk = 0; kk < 8; ++kk)
      *(half8*)&xstage[rt * 16 + lm][kk * 32 + lh * 8] = afr[kk];
  }
  __syncthreads();

  f32x4 z[8];
#pragma unroll
  for (int j = 0; j < 8; ++j) z[j] = (f32x4){0.f, 0.f, 0.f, 0.f};
#pragma unroll
  for (int kk = 0; kk < 8; ++kk) {
    half8 bfr[8];
#pragma unroll
    for (int j = 0; j < 8; ++j) {
      const int ct = ch * 8 + j;
      bfr[j] = *(const half8*)&VhB[((size_t)(ct * 8 + kk) * 64 + l) * 8];
    }
#pragma unroll
    for (int j = 0; j < 8; ++j)
      z[j] = __builtin_amdgcn_mfma_f32_16x16x32_f16(afr[kk], bfr[j], z[j], 0, 0, 0);
  }

  float dp[4] = {}, dxx[4] = {}, dux[4] = {};
#pragma unroll
  for (int j = 0; j < 8; ++j) {
    const int col = (ch * 8 + j) * 16 + lm;
    const float uu = ubuf[col];
#pragma unroll
    for (int r = 0; r < 4; ++r) {
      const int s = rt * 16 + lh * 4 + r;
      const float xv = __half2float(xstage[s][col]);
      dp[r]  = fmaf(z[j][r], xv, dp[r]);
      dxx[r] = fmaf(xv, xv, dxx[r]);
      dux[r] = fmaf(uu, xv, dux[r]);
    }
  }
#pragma unroll
  for (int off = 1; off < 16; off <<= 1)
#pragma unroll
    for (int r = 0; r < 4; ++r) {
      dp[r]  += __shfl_xor(dp[r], off);
      dxx[r] += __shfl_xor(dxx[r], off);
      dux[r] += __shfl_xor(dux[r], off);
    }
  if (lm == 0) {
#pragma unroll
    for (int r = 0; r < 4; ++r) {
      atomicAdd(&redbuf[rt][lh * 4 + r][0], dp[r]);
      atomicAdd(&redbuf[rt][lh * 4 + r][1], dxx[r]);
      atomicAdd(&redbuf[rt][lh * 4 + r][2], dux[r]);
    }
  }
  __syncthreads();
  if (tid < 32) {
    const float c0v = c0g[0];
    const int rr = tid >> 4, si = tid & 15;
    const float* rv = redbuf[rr][si];
    out[gb * 32 + rr * 16 + si] = 3.0f * rv[0] - rv[2] - 0.25f * c0v - rv[1];
  }
}

// ============================ launcher ======================================
extern "C" void kernel_launch(void* const* d_in, const int* in_sizes, int n_in,
                              void* d_out, int out_size, void* d_ws, size_t ws_size,
                              hipStream_t stream) {
  const float* E_ent   = (const float*)d_in[0];
  const float* E_rel   = (const float*)d_in[1];
  const float* W       = (const float*)d_in[2];
  const float* bvec    = (const float*)d_in[3];
  const int*   samples = (const int*)d_in[4];
  float* out = (float*)d_out;
  float* ws  = (float*)d_ws;

  float* VA = ws;                      // 65536 f32 (final V)
  float* VB = ws + 65536;              // NS scratch T
  float* VC = ws + 131072;             // NS intermediate
  float* ub = ws + 196608;             // 256
  float* c0 = ws + 196864;             // 1 (+pad)
  __half* VhB = (__half*)(ws + 197120);// 131072 f16 = 256 KB (fragment order)
  __half* XgA = (__half*)(ws + 262656);// 16.78M f16 = 33.5 MB (A fragments)

  phase1_kernel<<<511, 1024, 0, stream>>>(E_ent, E_rel, W, samples, VA, XgA);
  ns_mt_kernel<<<64, 64, 0, stream>>>(W, VA, VB);
  ns_upd_kernel<<<64, 64, 0, stream>>>(VA, VB, VC);
  ns_mt_kernel<<<64, 64, 0, stream>>>(W, VC, VB);
  ns_upd_kernel<<<64, 64, 0, stream>>>(VC, VB, VA);
  compute_u_kernel<<<1, 256, 0, stream>>>(VA, bvec, ub, c0);
  vhb_kernel<<<16, 1024, 0, stream>>>(VA, VhB);
  gemm_kernel<<<2048, 256, 0, stream>>>(XgA, VhB, ub, c0, out);
}